// Round 4
// baseline (2413.620 us; speedup 1.0000x reference)
//
#include <hip/hip_runtime.h>
#include <hip/hip_bf16.h>

typedef __hip_bfloat16 bf16_t;

#define NU 100000
#define NI 100000
#define NB_ 5000
#define NC_ 2000
#define NR_ 50000
#define NE 600000
#define NEB 100000
#define NEC 200000
#define NER 400000
#define NPERM (2 * NE + NEB + NEC + NER)   // 1,900,000
#define SCAN_N (2 * NU + NI + 1)           // 300,001 (user deg | item deg | rel deg | sentinel)
#define SCAN_CHUNK 2048
#define SCAN_NCHUNK ((SCAN_N + SCAN_CHUNK - 1) / SCAN_CHUNK)  // 147

__device__ __forceinline__ float b2f(bf16_t x) { return __bfloat162float(x); }
__device__ __forceinline__ float sane(float x) { return isfinite(x) ? x : 0.f; }

// dual-dtype load/store: external float tensors are f32 or bf16, per runtime flag
__device__ __forceinline__ float ldf(const void* p, size_t i, int f32) {
    return f32 ? ((const float*)p)[i] : __bfloat162float(((const bf16_t*)p)[i]);
}
__device__ __forceinline__ void stf(void* p, size_t i, float v, int f32) {
    if (f32) ((float*)p)[i] = v;
    else     ((bf16_t*)p)[i] = __float2bfloat16(v);
}

// ---- dtype probe: basis_freq[0] == 1.0f exactly; f32 word = 0x3F800000 ----
__global__ void detect_dtype(const unsigned int* w, int* flag) {
    if (threadIdx.x == 0 && blockIdx.x == 0) *flag = (w[0] == 0x3F800000u) ? 1 : 0;
}

// ---- wcomb_r = W_feat_r @ Wr_r (bf16 out, internal) ----
__global__ void combine_w(const void* Wb, const void* Wr0,
                          const void* Wc, const void* Wr1,
                          const void* Wr, const void* Wr2,
                          bf16_t* out, const int* flagp) {
    int f = *flagp;
    const void* A = blockIdx.x == 0 ? Wb : (blockIdx.x == 1 ? Wc : Wr);
    const void* B = blockIdx.x == 0 ? Wr0 : (blockIdx.x == 1 ? Wr1 : Wr2);
    bf16_t* O = out + (size_t)blockIdx.x * 4096;
    for (int idx = threadIdx.x; idx < 4096; idx += blockDim.x) {
        int i = idx >> 6, j = idx & 63;
        float acc = 0.f;
        for (int k = 0; k < 64; ++k)
            acc = fmaf(ldf(A, i * 64 + k, f), ldf(B, k * 64 + j, f), acc);
        O[idx] = __float2bfloat16(acc);
    }
}

// ---- Y[N,64] = X[N,64] @ W[64,64]; grid-stride so LDS staging amortizes ----
__global__ __launch_bounds__(256) void transform_rows(const void* __restrict__ X,
                                                      const void* __restrict__ W,
                                                      bf16_t* __restrict__ Y, int N,
                                                      const int* flagp, int w_internal) {
    __shared__ float Wl[64 * 64];
    int f = *flagp;
    int wf = w_internal ? 0 : f;
    for (int i = threadIdx.x; i < 4096; i += 256) Wl[i] = ldf(W, i, wf);
    __syncthreads();
    int lane = threadIdx.x & 63;
    int wave = threadIdx.x >> 6;
    for (int r = blockIdx.x * 4 + wave; r < N; r += gridDim.x * 4) {
        float rv = ldf(X, (size_t)r * 64 + lane, f);
        float acc = 0.f;
#pragma unroll
        for (int k = 0; k < 64; ++k) {
            float xk = __shfl(rv, k, 64);
            acc = fmaf(xk, Wl[k * 64 + lane], acc);
        }
        Y[(size_t)r * 64 + lane] = __float2bfloat16(acc);
    }
}

// ---- degree histograms ----
__global__ __launch_bounds__(256) void hist_purchase(const int* __restrict__ e_uid,
                                                     const int* __restrict__ e_iid,
                                                     int* __restrict__ deg) {
    int e = blockIdx.x * blockDim.x + threadIdx.x;
    if (e >= NE) return;
    atomicAdd(deg + e_uid[e], 1);
    atomicAdd(deg + NU + e_iid[e], 1);
}
__global__ __launch_bounds__(256) void hist_rel(const int* __restrict__ dst,
                                                int* __restrict__ deg, int n) {
    int e = blockIdx.x * blockDim.x + threadIdx.x;
    if (e < n) atomicAdd(deg + 2 * NU + dst[e], 1);
}

// ---- exclusive scan over SCAN_N ints (3 kernels) ----
__global__ __launch_bounds__(256) void scan1(const int* __restrict__ deg,
                                             int* __restrict__ off,
                                             int* __restrict__ ctot) {
    __shared__ int part[256];
    int base = blockIdx.x * SCAN_CHUNK + threadIdx.x * 8;
    int v[8]; int s = 0;
#pragma unroll
    for (int k = 0; k < 8; ++k) {
        int idx = base + k;
        v[k] = s;
        s += (idx < SCAN_N) ? deg[idx] : 0;
    }
    part[threadIdx.x] = s;
    __syncthreads();
    for (int o = 1; o < 256; o <<= 1) {
        int t = (threadIdx.x >= o) ? part[threadIdx.x - o] : 0;
        __syncthreads();
        part[threadIdx.x] += t;
        __syncthreads();
    }
    int texc = (threadIdx.x == 0) ? 0 : part[threadIdx.x - 1];
#pragma unroll
    for (int k = 0; k < 8; ++k) {
        int idx = base + k;
        if (idx < SCAN_N) off[idx] = texc + v[k];
    }
    if (threadIdx.x == 255) ctot[blockIdx.x] = part[255];
}
__global__ void scan2(const int* __restrict__ ctot, int* __restrict__ coff) {
    if (threadIdx.x == 0 && blockIdx.x == 0) {
        int s = 0;
        for (int i = 0; i < SCAN_NCHUNK; ++i) { coff[i] = s; s += ctot[i]; }
    }
}
__global__ __launch_bounds__(256) void scan3(int* __restrict__ off,
                                             const int* __restrict__ coff) {
    int add = coff[blockIdx.x];
    int base = blockIdx.x * SCAN_CHUNK + threadIdx.x;
#pragma unroll
    for (int k = 0; k < 8; ++k) {
        int idx = base + k * 256;
        if (idx < SCAN_N) off[idx] += add;
    }
}

// ---- scatter into perm (counting sort placement) ----
__global__ __launch_bounds__(256) void scatter_purchase(const int* __restrict__ e_uid,
                                                        const int* __restrict__ e_iid,
                                                        int* __restrict__ cur,
                                                        int* __restrict__ perm) {
    int e = blockIdx.x * blockDim.x + threadIdx.x;
    if (e >= NE) return;
    int p1 = atomicAdd(cur + e_uid[e], 1);
    perm[p1] = e;
    int p2 = atomicAdd(cur + NU + e_iid[e], 1);
    perm[p2] = e;
}
__global__ __launch_bounds__(256) void scatter_rel(const int* __restrict__ src,
                                                   const int* __restrict__ dst,
                                                   int* __restrict__ cur,
                                                   int* __restrict__ perm,
                                                   int n, int baseRow, int r) {
    int e = blockIdx.x * blockDim.x + threadIdx.x;
    if (e >= n) return;
    int p = atomicAdd(cur + 2 * NU + dst[e], 1);
    perm[p] = ((src[e] + baseRow) << 2) | r;
}

// ---- fused user: gather edges, single-pass softmax, gate GEMV, elu, store ----
__global__ __launch_bounds__(256) void fused_user(
    const bf16_t* __restrict__ uh, const bf16_t* __restrict__ ih,
    const void* __restrict__ u_pos, const void* __restrict__ u_pos_k,
    const void* __restrict__ basis_freq, const void* __restrict__ phase,
    const void* __restrict__ e_time,
    const int* __restrict__ e_iid, const int* __restrict__ pos_u,
    const int* __restrict__ off, const int* __restrict__ perm,
    const void* __restrict__ Wg_u, const void* __restrict__ user_h,
    void* __restrict__ out, const int* flagp) {
    __shared__ bf16_t Wl[128 * 64];      // 16 KB
    __shared__ float posk[50 * 64];      // 12.8 KB
    __shared__ float posv[50 * 64];      // 12.8 KB
    int f = *flagp;
    for (int i = threadIdx.x; i < 128 * 64; i += 256) Wl[i] = __float2bfloat16(ldf(Wg_u, i, f));
    for (int i = threadIdx.x; i < 50 * 64; i += 256) {
        posk[i] = ldf(u_pos_k, i, f);
        posv[i] = ldf(u_pos, i, f);
    }
    __syncthreads();
    int lane = threadIdx.x & 63;
    int wave = threadIdx.x >> 6;
    int u = blockIdx.x * 4 + wave;
    if (u >= NU) return;
    float bfq = ldf(basis_freq, lane, f), ph = ldf(phase, lane, f);
    float hu = b2f(uh[(size_t)u * 64 + lane]);
    int j0 = off[u], j1 = off[u + 1];
    float s1 = 0.f, s2 = 0.f, a0 = 0.f, a1 = 0.f;
    for (int j = j0; j < j1; ++j) {
        int e = perm[j];
        int iid = e_iid[e];
        int pu = pos_u[e];
        float t = ldf(e_time, e, f);
        float te = cosf(fmaf(t, bfq, ph));
        float hi = b2f(ih[(size_t)iid * 64 + lane]);
        float d1 = (hi + posk[pu * 64 + lane] + te) * hu;
        float d2 = hi * hu;
#pragma unroll
        for (int o = 32; o; o >>= 1) {
            d1 += __shfl_xor(d1, o, 64);
            d2 += __shfl_xor(d2, o, 64);
        }
        float p1 = expf(fminf(d1 * 0.125f, 50.f));
        float p2 = expf(fminf(d2 * 0.125f, 50.f));
        s1 += p1; s2 += p2;
        a0 = fmaf(p1, hi + posv[pu * 64 + lane], a0);
        a1 = fmaf(p2, hi, a1);
    }
    a0 *= 1.f / (s1 + 1e-9f);
    a1 *= 1.f / (s2 + 1e-9f);
    float s = ldf(user_h, (size_t)u * 64 + lane, f);
#pragma unroll
    for (int k = 0; k < 64; ++k) {
        s = fmaf(__shfl(a0, k, 64), b2f(Wl[k * 64 + lane]), s);
        s = fmaf(__shfl(a1, k, 64), b2f(Wl[(64 + k) * 64 + lane]), s);
    }
    float v = s > 0.f ? s : expm1f(s);
    stf(out, (size_t)u * 64 + lane, sane(v), f);
}

// ---- fused item: purchase gather + relation-mean gather + gate GEMV + elu ----
__global__ __launch_bounds__(256) void fused_item(
    const bf16_t* __restrict__ uh, const bf16_t* __restrict__ ih,
    const void* __restrict__ i_pos, const void* __restrict__ i_pos_k,
    const void* __restrict__ basis_freq, const void* __restrict__ phase,
    const void* __restrict__ e_time,
    const int* __restrict__ e_uid, const int* __restrict__ pos_i,
    const int* __restrict__ off, const int* __restrict__ perm,
    const bf16_t* __restrict__ fW,
    const void* __restrict__ Wg_i, const void* __restrict__ item_h,
    void* __restrict__ out, const int* flagp) {
    __shared__ bf16_t Wl[128 * 64];
    __shared__ float posk[50 * 64];
    __shared__ float posv[50 * 64];
    int f = *flagp;
    for (int i = threadIdx.x; i < 128 * 64; i += 256) Wl[i] = __float2bfloat16(ldf(Wg_i, i, f));
    for (int i = threadIdx.x; i < 50 * 64; i += 256) {
        posk[i] = ldf(i_pos_k, i, f);
        posv[i] = ldf(i_pos, i, f);
    }
    __syncthreads();
    int lane = threadIdx.x & 63;
    int wave = threadIdx.x >> 6;
    int it = blockIdx.x * 4 + wave;
    if (it >= NI) return;
    float bfq = ldf(basis_freq, lane, f), ph = ldf(phase, lane, f);
    float hi_s = b2f(ih[(size_t)it * 64 + lane]);
    // purchase side
    int j0 = off[NU + it], j1 = off[NU + it + 1];
    float s1 = 0.f, s2 = 0.f, a0 = 0.f, a1 = 0.f;
    for (int j = j0; j < j1; ++j) {
        int e = perm[j];
        int uid = e_uid[e];
        int pi = pos_i[e];
        float t = ldf(e_time, e, f);
        float te = cosf(fmaf(t, bfq, ph));
        float hu = b2f(uh[(size_t)uid * 64 + lane]);
        float d1 = (hu + posk[pi * 64 + lane] + te) * hi_s;
        float d2 = hu * hi_s;
#pragma unroll
        for (int o = 32; o; o >>= 1) {
            d1 += __shfl_xor(d1, o, 64);
            d2 += __shfl_xor(d2, o, 64);
        }
        float p1 = expf(fminf(d1 * 0.125f, 50.f));
        float p2 = expf(fminf(d2 * 0.125f, 50.f));
        s1 += p1; s2 += p2;
        a0 = fmaf(p1, hu + posv[pi * 64 + lane], a0);
        a1 = fmaf(p2, hu, a1);
    }
    a0 *= 1.f / (s1 + 1e-9f);
    a1 *= 1.f / (s2 + 1e-9f);
    // relation side (merged; rel id in low 2 bits)
    int r0c = 0, r1c = 0, r2c = 0;
    float r0 = 0.f, r1 = 0.f, r2 = 0.f;
    int k0 = off[2 * NU + it], k1 = off[2 * NU + it + 1];
    for (int j = k0; j < k1; ++j) {
        int v = perm[j];
        int r = v & 3;
        float fv = b2f(fW[(size_t)(v >> 2) * 64 + lane]);
        if (r == 0)      { r0 += fv; r0c++; }
        else if (r == 1) { r1 += fv; r1c++; }
        else             { r2 += fv; r2c++; }
    }
    float rel = r0 * (1.f / fmaxf((float)r0c, 1.f))
              + r1 * (1.f / fmaxf((float)r1c, 1.f))
              + r2 * (1.f / fmaxf((float)r2c, 1.f));
    float s = ldf(item_h, (size_t)it * 64 + lane, f) + rel;
#pragma unroll
    for (int k = 0; k < 64; ++k) {
        s = fmaf(__shfl(a0, k, 64), b2f(Wl[k * 64 + lane]), s);
        s = fmaf(__shfl(a1, k, 64), b2f(Wl[(64 + k) * 64 + lane]), s);
    }
    float v = s > 0.f ? s : expm1f(s);
    stf(out, (size_t)(NU + it) * 64 + lane, sane(v), f);
}

extern "C" void kernel_launch(void* const* d_in, const int* in_sizes, int n_in,
                              void* d_out, int out_size, void* d_ws, size_t ws_size,
                              hipStream_t stream) {
    const void* user_h     = d_in[0];
    const void* item_h     = d_in[1];
    const void* brand_feat = d_in[2];
    const void* cat_feat   = d_in[3];
    const void* rel_feat   = d_in[4];
    const void* Wu   = d_in[5];
    const void* Wi   = d_in[6];
    const void* Wb   = d_in[7];
    const void* Wc   = d_in[8];
    const void* Wr   = d_in[9];
    const void* Wg_u = d_in[10];
    const void* Wg_i = d_in[11];
    const void* u_pos   = d_in[12];
    const void* u_pos_k = d_in[13];
    const void* i_pos   = d_in[14];
    const void* i_pos_k = d_in[15];
    const void* basis_freq = d_in[16];
    const void* phase      = d_in[17];
    const void* Wr0 = d_in[18];
    const void* Wr1 = d_in[19];
    const void* Wr2 = d_in[20];
    const void* e_time = d_in[21];
    const int* e_iid  = (const int*)d_in[22];
    const int* e_uid  = (const int*)d_in[23];
    const int* pos_u  = (const int*)d_in[24];
    const int* pos_i  = (const int*)d_in[25];
    const int* eb_src = (const int*)d_in[26];
    const int* eb_dst = (const int*)d_in[27];
    const int* ec_src = (const int*)d_in[28];
    const int* ec_dst = (const int*)d_in[29];
    const int* er_src = (const int*)d_in[30];
    const int* er_dst = (const int*)d_in[31];

    char* base = (char*)d_ws;
    size_t off_b = 0;
    auto alloc = [&](size_t bytes) { size_t p = off_b; off_b = (off_b + bytes + 511) & ~(size_t)511; return p; };
    size_t o_flag  = alloc(512);
    size_t o_uh    = alloc((size_t)NU * 64 * 2);
    size_t o_ih    = alloc((size_t)NI * 64 * 2);
    size_t o_fW    = alloc((size_t)(NB_ + NC_ + NR_) * 64 * 2);
    size_t o_wcomb = alloc((size_t)3 * 4096 * 2);
    size_t o_deg   = alloc((size_t)SCAN_N * 4);
    size_t o_off   = alloc((size_t)SCAN_N * 4);
    size_t o_cur   = alloc((size_t)SCAN_N * 4);
    size_t o_ctot  = alloc((size_t)SCAN_NCHUNK * 4);
    size_t o_coff  = alloc((size_t)SCAN_NCHUNK * 4);
    size_t o_perm  = alloc((size_t)NPERM * 4);

    int*    flagp = (int*)(base + o_flag);
    bf16_t* uh    = (bf16_t*)(base + o_uh);
    bf16_t* ih    = (bf16_t*)(base + o_ih);
    bf16_t* fW    = (bf16_t*)(base + o_fW);
    bf16_t* wcomb = (bf16_t*)(base + o_wcomb);
    int*    deg   = (int*)(base + o_deg);
    int*    offp  = (int*)(base + o_off);
    int*    cur   = (int*)(base + o_cur);
    int*    ctot  = (int*)(base + o_ctot);
    int*    coff  = (int*)(base + o_coff);
    int*    perm  = (int*)(base + o_perm);

    hipMemsetAsync(deg, 0, (size_t)SCAN_N * 4, stream);
    detect_dtype<<<1, 64, 0, stream>>>((const unsigned int*)basis_freq, flagp);

    combine_w<<<3, 256, 0, stream>>>(Wb, Wr0, Wc, Wr1, Wr, Wr2, wcomb, flagp);
    transform_rows<<<2048, 256, 0, stream>>>(user_h, Wu, uh, NU, flagp, 0);
    transform_rows<<<2048, 256, 0, stream>>>(item_h, Wi, ih, NI, flagp, 0);
    transform_rows<<<512, 256, 0, stream>>>(brand_feat, wcomb, fW, NB_, flagp, 1);
    transform_rows<<<256, 256, 0, stream>>>(cat_feat, wcomb + 4096, fW + (size_t)NB_ * 64, NC_, flagp, 1);
    transform_rows<<<1024, 256, 0, stream>>>(rel_feat, wcomb + 8192, fW + (size_t)(NB_ + NC_) * 64, NR_, flagp, 1);

    hist_purchase<<<(NE + 255) / 256, 256, 0, stream>>>(e_uid, e_iid, deg);
    hist_rel<<<(NEB + 255) / 256, 256, 0, stream>>>(eb_dst, deg, NEB);
    hist_rel<<<(NEC + 255) / 256, 256, 0, stream>>>(ec_dst, deg, NEC);
    hist_rel<<<(NER + 255) / 256, 256, 0, stream>>>(er_dst, deg, NER);

    scan1<<<SCAN_NCHUNK, 256, 0, stream>>>(deg, offp, ctot);
    scan2<<<1, 64, 0, stream>>>(ctot, coff);
    scan3<<<SCAN_NCHUNK, 256, 0, stream>>>(offp, coff);

    hipMemcpyAsync(cur, offp, (size_t)SCAN_N * 4, hipMemcpyDeviceToDevice, stream);

    scatter_purchase<<<(NE + 255) / 256, 256, 0, stream>>>(e_uid, e_iid, cur, perm);
    scatter_rel<<<(NEB + 255) / 256, 256, 0, stream>>>(eb_src, eb_dst, cur, perm, NEB, 0, 0);
    scatter_rel<<<(NEC + 255) / 256, 256, 0, stream>>>(ec_src, ec_dst, cur, perm, NEC, NB_, 1);
    scatter_rel<<<(NER + 255) / 256, 256, 0, stream>>>(er_src, er_dst, cur, perm, NER, NB_ + NC_, 2);

    fused_user<<<(NU + 3) / 4, 256, 0, stream>>>(uh, ih, u_pos, u_pos_k, basis_freq, phase,
                                                 e_time, e_iid, pos_u, offp, perm,
                                                 Wg_u, user_h, d_out, flagp);
    fused_item<<<(NI + 3) / 4, 256, 0, stream>>>(uh, ih, i_pos, i_pos_k, basis_freq, phase,
                                                 e_time, e_uid, pos_i, offp, perm, fW,
                                                 Wg_i, item_h, d_out, flagp);
}

// Round 5
// 1601.906 us; speedup vs baseline: 1.5067x; 1.5067x over previous
//
#include <hip/hip_runtime.h>
#include <hip/hip_bf16.h>

typedef __hip_bfloat16 bf16_t;

#define NU 100000
#define NI 100000
#define NB_ 5000
#define NC_ 2000
#define NR_ 50000
#define NE 600000
#define NEB 100000
#define NEC 200000
#define NER 400000
#define NPERM (2 * NE + NEB + NEC + NER)   // 1,900,000
#define NALL (NE + NEB + NEC + NER)        // 1,300,000 scatter threads
#define SCAN_N (2 * NU + NI + 1)
#define SCAN_CHUNK 2048
#define SCAN_NCHUNK ((SCAN_N + SCAN_CHUNK - 1) / SCAN_CHUNK)

// transform_all segmented grid
#define TRU 1024
#define TRI 1024
#define TRB 128
#define TRC 64
#define TRR 512
#define TRTOT (TRU + TRI + TRB + TRC + TRR)

#define UBLK ((NU + 3) / 4)
#define IBLK ((NI + 3) / 4)

__device__ __forceinline__ float b2f(bf16_t x) { return __bfloat162float(x); }
__device__ __forceinline__ float sane(float x) { return isfinite(x) ? x : 0.f; }

// dual-dtype load/store: external float tensors are f32 or bf16, per runtime flag
__device__ __forceinline__ float ldf(const void* p, size_t i, int f32) {
    return f32 ? ((const float*)p)[i] : __bfloat162float(((const bf16_t*)p)[i]);
}
__device__ __forceinline__ void stf(void* p, size_t i, float v, int f32) {
    if (f32) ((float*)p)[i] = v;
    else     ((bf16_t*)p)[i] = __float2bfloat16(v);
}

// ---- dtype probe: basis_freq[0] == 1.0f exactly; f32 word = 0x3F800000 ----
__global__ void detect_dtype(const unsigned int* w, int* flag) {
    if (threadIdx.x == 0 && blockIdx.x == 0) *flag = (w[0] == 0x3F800000u) ? 1 : 0;
}

// ---- wcomb_r = W_feat_r @ Wr_r (bf16 out, internal) ----
__global__ void combine_w(const void* Wb, const void* Wr0,
                          const void* Wc, const void* Wr1,
                          const void* Wr, const void* Wr2,
                          bf16_t* out, const int* flagp) {
    int f = *flagp;
    const void* A = blockIdx.x == 0 ? Wb : (blockIdx.x == 1 ? Wc : Wr);
    const void* B = blockIdx.x == 0 ? Wr0 : (blockIdx.x == 1 ? Wr1 : Wr2);
    bf16_t* O = out + (size_t)blockIdx.x * 4096;
    for (int idx = threadIdx.x; idx < 4096; idx += blockDim.x) {
        int i = idx >> 6, j = idx & 63;
        float acc = 0.f;
        for (int k = 0; k < 64; ++k)
            acc = fmaf(ldf(A, i * 64 + k, f), ldf(B, k * 64 + j, f), acc);
        O[idx] = __float2bfloat16(acc);
    }
}

// ---- all five row transforms in one segmented launch ----
__global__ __launch_bounds__(256) void transform_all(
    const void* __restrict__ user_h, const void* __restrict__ item_h,
    const void* __restrict__ brand_feat, const void* __restrict__ cat_feat,
    const void* __restrict__ rel_feat,
    const void* __restrict__ Wu, const void* __restrict__ Wi,
    const bf16_t* __restrict__ wcomb,
    bf16_t* __restrict__ uh, bf16_t* __restrict__ ih, bf16_t* __restrict__ fW,
    const int* flagp) {
    __shared__ float Wl[4096];
    int f = *flagp;
    int b = blockIdx.x;
    const void* X; const void* W; int wint; bf16_t* Y; int N; int nb; int b0;
    if (b < TRU)                         { X = user_h;    W = Wu;          wint = 0; Y = uh; N = NU;  nb = TRU; b0 = b; }
    else if (b < TRU + TRI)              { X = item_h;    W = Wi;          wint = 0; Y = ih; N = NI;  nb = TRI; b0 = b - TRU; }
    else if (b < TRU + TRI + TRB)        { X = brand_feat; W = wcomb;      wint = 1; Y = fW; N = NB_; nb = TRB; b0 = b - TRU - TRI; }
    else if (b < TRU + TRI + TRB + TRC)  { X = cat_feat;  W = wcomb + 4096; wint = 1; Y = fW + (size_t)NB_ * 64; N = NC_; nb = TRC; b0 = b - TRU - TRI - TRB; }
    else                                 { X = rel_feat;  W = wcomb + 8192; wint = 1; Y = fW + (size_t)(NB_ + NC_) * 64; N = NR_; nb = TRR; b0 = b - TRU - TRI - TRB - TRC; }
    for (int i = threadIdx.x; i < 4096; i += 256)
        Wl[i] = wint ? b2f(((const bf16_t*)W)[i]) : ldf(W, i, f);
    __syncthreads();
    int lane = threadIdx.x & 63;
    int wave = threadIdx.x >> 6;
    for (int r = b0 * 4 + wave; r < N; r += nb * 4) {
        float rv = ldf(X, (size_t)r * 64 + lane, f);
        float acc = 0.f;
#pragma unroll
        for (int k = 0; k < 64; ++k)
            acc = fmaf(__shfl(rv, k, 64), Wl[k * 64 + lane], acc);
        Y[(size_t)r * 64 + lane] = __float2bfloat16(acc);
    }
}

// ---- one-launch degree histogram over all edge sets ----
__global__ __launch_bounds__(256) void hist_all(
    const int* __restrict__ e_uid, const int* __restrict__ e_iid,
    const int* __restrict__ eb_dst, const int* __restrict__ ec_dst,
    const int* __restrict__ er_dst, int* __restrict__ deg) {
    int t = blockIdx.x * blockDim.x + threadIdx.x;
    if (t < NE) {
        atomicAdd(deg + e_uid[t], 1);
        atomicAdd(deg + NU + e_iid[t], 1);
    } else if (t < NE + NEB) {
        atomicAdd(deg + 2 * NU + eb_dst[t - NE], 1);
    } else if (t < NE + NEB + NEC) {
        atomicAdd(deg + 2 * NU + ec_dst[t - NE - NEB], 1);
    } else if (t < NALL) {
        atomicAdd(deg + 2 * NU + er_dst[t - NE - NEB - NEC], 1);
    }
}

// ---- exclusive scan over SCAN_N ints ----
__global__ __launch_bounds__(256) void scan1(const int* __restrict__ deg,
                                             int* __restrict__ off,
                                             int* __restrict__ ctot) {
    __shared__ int part[256];
    int base = blockIdx.x * SCAN_CHUNK + threadIdx.x * 8;
    int v[8]; int s = 0;
#pragma unroll
    for (int k = 0; k < 8; ++k) {
        int idx = base + k;
        v[k] = s;
        s += (idx < SCAN_N) ? deg[idx] : 0;
    }
    part[threadIdx.x] = s;
    __syncthreads();
    for (int o = 1; o < 256; o <<= 1) {
        int t = (threadIdx.x >= o) ? part[threadIdx.x - o] : 0;
        __syncthreads();
        part[threadIdx.x] += t;
        __syncthreads();
    }
    int texc = (threadIdx.x == 0) ? 0 : part[threadIdx.x - 1];
#pragma unroll
    for (int k = 0; k < 8; ++k) {
        int idx = base + k;
        if (idx < SCAN_N) off[idx] = texc + v[k];
    }
    if (threadIdx.x == 255) ctot[blockIdx.x] = part[255];
}
__global__ void scan2(const int* __restrict__ ctot, int* __restrict__ coff) {
    if (threadIdx.x == 0 && blockIdx.x == 0) {
        int s = 0;
        for (int i = 0; i < SCAN_NCHUNK; ++i) { coff[i] = s; s += ctot[i]; }
    }
}
__global__ __launch_bounds__(256) void scan3(int* __restrict__ off,
                                             const int* __restrict__ coff) {
    int add = coff[blockIdx.x];
    int base = blockIdx.x * SCAN_CHUNK + threadIdx.x;
#pragma unroll
    for (int k = 0; k < 8; ++k) {
        int idx = base + k * 256;
        if (idx < SCAN_N) off[idx] += add;
    }
}

// ---- one-launch payload scatter: perm[slot] = {nbr | pos<<17 (| rel<<17), time} ----
__global__ __launch_bounds__(256) void scatter_all(
    const int* __restrict__ e_uid, const int* __restrict__ e_iid,
    const int* __restrict__ pos_u, const int* __restrict__ pos_i,
    const void* __restrict__ e_time,
    const int* __restrict__ eb_src, const int* __restrict__ eb_dst,
    const int* __restrict__ ec_src, const int* __restrict__ ec_dst,
    const int* __restrict__ er_src, const int* __restrict__ er_dst,
    int* __restrict__ cur, uint2* __restrict__ perm, const int* flagp) {
    int f = *flagp;
    int t = blockIdx.x * blockDim.x + threadIdx.x;
    if (t < NE) {
        int uid = e_uid[t], iid = e_iid[t];
        unsigned ty = __float_as_uint(ldf(e_time, t, f));
        int p1 = atomicAdd(cur + uid, 1);
        perm[p1] = make_uint2((unsigned)iid | ((unsigned)pos_u[t] << 17), ty);
        int p2 = atomicAdd(cur + NU + iid, 1);
        perm[p2] = make_uint2((unsigned)uid | ((unsigned)pos_i[t] << 17), ty);
    } else if (t < NE + NEB) {
        int e = t - NE;
        int p = atomicAdd(cur + 2 * NU + eb_dst[e], 1);
        perm[p] = make_uint2((unsigned)eb_src[e], 0u);
    } else if (t < NE + NEB + NEC) {
        int e = t - NE - NEB;
        int p = atomicAdd(cur + 2 * NU + ec_dst[e], 1);
        perm[p] = make_uint2((unsigned)(ec_src[e] + NB_) | (1u << 17), 0u);
    } else if (t < NALL) {
        int e = t - NE - NEB - NEC;
        int p = atomicAdd(cur + 2 * NU + er_dst[e], 1);
        perm[p] = make_uint2((unsigned)(er_src[e] + NB_ + NC_) | (2u << 17), 0u);
    }
}

// ---- fused per-vertex gather: softmax agg + (item: relation means) + gate GEMV + elu ----
__global__ __launch_bounds__(256) void fused_all(
    const bf16_t* __restrict__ uh, const bf16_t* __restrict__ ih,
    const void* __restrict__ u_pos, const void* __restrict__ u_pos_k,
    const void* __restrict__ i_pos, const void* __restrict__ i_pos_k,
    const void* __restrict__ basis_freq, const void* __restrict__ phase,
    const int* __restrict__ off, const uint2* __restrict__ perm,
    const bf16_t* __restrict__ fW,
    const void* __restrict__ Wg_u, const void* __restrict__ Wg_i,
    const void* __restrict__ user_h, const void* __restrict__ item_h,
    void* __restrict__ out, const int* flagp) {
    __shared__ bf16_t Wl[128 * 64];     // 16 KB
    __shared__ bf16_t poskL[50 * 64];   // 6.4 KB
    __shared__ bf16_t posvL[50 * 64];   // 6.4 KB
    int f = *flagp;
    bool isU = blockIdx.x < UBLK;
    const void* Wg = isU ? Wg_u : Wg_i;
    const void* pk = isU ? u_pos_k : i_pos_k;
    const void* pv = isU ? u_pos : i_pos;
    for (int i = threadIdx.x; i < 128 * 64; i += 256) Wl[i] = __float2bfloat16(ldf(Wg, i, f));
    for (int i = threadIdx.x; i < 50 * 64; i += 256) {
        poskL[i] = __float2bfloat16(ldf(pk, i, f));
        posvL[i] = __float2bfloat16(ldf(pv, i, f));
    }
    __syncthreads();
    int lane = threadIdx.x & 63;
    int wave = threadIdx.x >> 6;
    int blk = isU ? blockIdx.x : blockIdx.x - UBLK;
    int vtx = blk * 4 + wave;
    if (vtx >= (isU ? NU : NI)) return;
    const bf16_t* other = isU ? ih : uh;
    float bfq = ldf(basis_freq, lane, f), ph = ldf(phase, lane, f);
    float hs = isU ? b2f(uh[(size_t)vtx * 64 + lane]) : b2f(ih[(size_t)vtx * 64 + lane]);
    int seg = isU ? vtx : NU + vtx;
    int j0 = off[seg], j1 = off[seg + 1];
    float s1 = 0.f, s2 = 0.f, a0 = 0.f, a1 = 0.f;
    for (int cb = j0; cb < j1; cb += 64) {
        int m = j1 - cb; if (m > 64) m = 64;
        uint2 pay = make_uint2(0u, 0u);
        if (lane < m) pay = perm[cb + lane];
        // software pipeline: broadcast payload k+1 + issue its row load while computing k
        unsigned px0 = (unsigned)__shfl((int)pay.x, 0, 64);
        unsigned py0 = (unsigned)__shfl((int)pay.y, 0, 64);
        int nbr0 = px0 & 0x1FFFF; int pos0 = (px0 >> 17) & 63;
        float ho0 = b2f(other[(size_t)nbr0 * 64 + lane]);
        for (int k = 0; k < m; ++k) {
            unsigned px1 = 0, py1 = 0; int nbr1 = 0, pos1 = 0; float ho1 = 0.f;
            if (k + 1 < m) {
                px1 = (unsigned)__shfl((int)pay.x, k + 1, 64);
                py1 = (unsigned)__shfl((int)pay.y, k + 1, 64);
                nbr1 = px1 & 0x1FFFF; pos1 = (px1 >> 17) & 63;
                ho1 = b2f(other[(size_t)nbr1 * 64 + lane]);
            }
            float t = __uint_as_float(py0);
            float te = __cosf(fmaf(t, bfq, ph));
            float d1 = (ho0 + b2f(poskL[pos0 * 64 + lane]) + te) * hs;
            float d2 = ho0 * hs;
#pragma unroll
            for (int o = 32; o; o >>= 1) {
                d1 += __shfl_xor(d1, o, 64);
                d2 += __shfl_xor(d2, o, 64);
            }
            float p1 = __expf(fminf(d1 * 0.125f, 50.f));
            float p2 = __expf(fminf(d2 * 0.125f, 50.f));
            s1 += p1; s2 += p2;
            a0 = fmaf(p1, ho0 + b2f(posvL[pos0 * 64 + lane]), a0);
            a1 = fmaf(p2, ho0, a1);
            px0 = px1; py0 = py1; nbr0 = nbr1; pos0 = pos1; ho0 = ho1;
        }
    }
    a0 *= 1.f / (s1 + 1e-9f);
    a1 *= 1.f / (s2 + 1e-9f);
    float relv = 0.f;
    if (!isU) {
        int k0 = off[2 * NU + vtx], k1 = off[2 * NU + vtx + 1];
        float r0 = 0.f, r1 = 0.f, r2 = 0.f; int c0 = 0, c1 = 0, c2 = 0;
        for (int cb = k0; cb < k1; cb += 64) {
            int m = k1 - cb; if (m > 64) m = 64;
            unsigned px = (lane < m) ? perm[cb + lane].x : 0u;
            for (int k = 0; k < m; ++k) {
                unsigned u = (unsigned)__shfl((int)px, k, 64);
                int row = u & 0x1FFFF; int r = (u >> 17) & 3;
                float fv = b2f(fW[(size_t)row * 64 + lane]);
                if (r == 0)      { r0 += fv; c0++; }
                else if (r == 1) { r1 += fv; c1++; }
                else             { r2 += fv; c2++; }
            }
        }
        relv = r0 * (1.f / fmaxf((float)c0, 1.f))
             + r1 * (1.f / fmaxf((float)c1, 1.f))
             + r2 * (1.f / fmaxf((float)c2, 1.f));
    }
    const void* hself = isU ? user_h : item_h;
    float s = ldf(hself, (size_t)vtx * 64 + lane, f) + relv;
#pragma unroll
    for (int k = 0; k < 64; ++k) {
        s = fmaf(__shfl(a0, k, 64), b2f(Wl[k * 64 + lane]), s);
        s = fmaf(__shfl(a1, k, 64), b2f(Wl[(64 + k) * 64 + lane]), s);
    }
    float v = s > 0.f ? s : expm1f(s);
    size_t orow = isU ? (size_t)vtx : (size_t)(NU + vtx);
    stf(out, orow * 64 + lane, sane(v), f);
}

extern "C" void kernel_launch(void* const* d_in, const int* in_sizes, int n_in,
                              void* d_out, int out_size, void* d_ws, size_t ws_size,
                              hipStream_t stream) {
    const void* user_h     = d_in[0];
    const void* item_h     = d_in[1];
    const void* brand_feat = d_in[2];
    const void* cat_feat   = d_in[3];
    const void* rel_feat   = d_in[4];
    const void* Wu   = d_in[5];
    const void* Wi   = d_in[6];
    const void* Wb   = d_in[7];
    const void* Wc   = d_in[8];
    const void* Wr   = d_in[9];
    const void* Wg_u = d_in[10];
    const void* Wg_i = d_in[11];
    const void* u_pos   = d_in[12];
    const void* u_pos_k = d_in[13];
    const void* i_pos   = d_in[14];
    const void* i_pos_k = d_in[15];
    const void* basis_freq = d_in[16];
    const void* phase      = d_in[17];
    const void* Wr0 = d_in[18];
    const void* Wr1 = d_in[19];
    const void* Wr2 = d_in[20];
    const void* e_time = d_in[21];
    const int* e_iid  = (const int*)d_in[22];
    const int* e_uid  = (const int*)d_in[23];
    const int* pos_u  = (const int*)d_in[24];
    const int* pos_i  = (const int*)d_in[25];
    const int* eb_src = (const int*)d_in[26];
    const int* eb_dst = (const int*)d_in[27];
    const int* ec_src = (const int*)d_in[28];
    const int* ec_dst = (const int*)d_in[29];
    const int* er_src = (const int*)d_in[30];
    const int* er_dst = (const int*)d_in[31];

    char* base = (char*)d_ws;
    size_t off_b = 0;
    auto alloc = [&](size_t bytes) { size_t p = off_b; off_b = (off_b + bytes + 511) & ~(size_t)511; return p; };
    size_t o_flag  = alloc(512);
    size_t o_uh    = alloc((size_t)NU * 64 * 2);
    size_t o_ih    = alloc((size_t)NI * 64 * 2);
    size_t o_fW    = alloc((size_t)(NB_ + NC_ + NR_) * 64 * 2);
    size_t o_wcomb = alloc((size_t)3 * 4096 * 2);
    size_t o_deg   = alloc((size_t)SCAN_N * 4);
    size_t o_off   = alloc((size_t)SCAN_N * 4);
    size_t o_cur   = alloc((size_t)SCAN_N * 4);
    size_t o_ctot  = alloc((size_t)SCAN_NCHUNK * 4);
    size_t o_coff  = alloc((size_t)SCAN_NCHUNK * 4);
    size_t o_perm  = alloc((size_t)NPERM * 8);

    int*    flagp = (int*)(base + o_flag);
    bf16_t* uh    = (bf16_t*)(base + o_uh);
    bf16_t* ih    = (bf16_t*)(base + o_ih);
    bf16_t* fW    = (bf16_t*)(base + o_fW);
    bf16_t* wcomb = (bf16_t*)(base + o_wcomb);
    int*    deg   = (int*)(base + o_deg);
    int*    offp  = (int*)(base + o_off);
    int*    cur   = (int*)(base + o_cur);
    int*    ctot  = (int*)(base + o_ctot);
    int*    coff  = (int*)(base + o_coff);
    uint2*  perm  = (uint2*)(base + o_perm);

    hipMemsetAsync(deg, 0, (size_t)SCAN_N * 4, stream);
    detect_dtype<<<1, 64, 0, stream>>>((const unsigned int*)basis_freq, flagp);

    combine_w<<<3, 256, 0, stream>>>(Wb, Wr0, Wc, Wr1, Wr, Wr2, wcomb, flagp);
    transform_all<<<TRTOT, 256, 0, stream>>>(user_h, item_h, brand_feat, cat_feat, rel_feat,
                                             Wu, Wi, wcomb, uh, ih, fW, flagp);

    hist_all<<<(NALL + 255) / 256, 256, 0, stream>>>(e_uid, e_iid, eb_dst, ec_dst, er_dst, deg);

    scan1<<<SCAN_NCHUNK, 256, 0, stream>>>(deg, offp, ctot);
    scan2<<<1, 64, 0, stream>>>(ctot, coff);
    scan3<<<SCAN_NCHUNK, 256, 0, stream>>>(offp, coff);

    hipMemcpyAsync(cur, offp, (size_t)SCAN_N * 4, hipMemcpyDeviceToDevice, stream);

    scatter_all<<<(NALL + 255) / 256, 256, 0, stream>>>(e_uid, e_iid, pos_u, pos_i, e_time,
                                                        eb_src, eb_dst, ec_src, ec_dst,
                                                        er_src, er_dst, cur, perm, flagp);

    fused_all<<<UBLK + IBLK, 256, 0, stream>>>(uh, ih, u_pos, u_pos_k, i_pos, i_pos_k,
                                               basis_freq, phase, offp, perm, fW,
                                               Wg_u, Wg_i, user_h, item_h, d_out, flagp);
}

// Round 6
// 1336.529 us; speedup vs baseline: 1.8059x; 1.1986x over previous
//
#include <hip/hip_runtime.h>
#include <hip/hip_bf16.h>
#include <hip/hip_fp16.h>

typedef __hip_bfloat16 bf16_t;

#define NU 100000
#define NI 100000
#define NB_ 5000
#define NC_ 2000
#define NR_ 50000
#define NE 600000
#define NEB 100000
#define NEC 200000
#define NER 400000
#define NPERM (2 * NE + NEB + NEC + NER)   // 1,900,000
#define NRELE (NEB + NEC + NER)            // 700,000
#define NALL (NE + NRELE)
#define SCAN_N (2 * NU + NI + 1)
#define SCAN_CHUNK 2048
#define SCAN_NCHUNK ((SCAN_N + SCAN_CHUNK - 1) / SCAN_CHUNK)
#define VBLK ((NU + 3) / 4)                // gather blocks per phase (NU==NI)

typedef __attribute__((ext_vector_type(8))) short short8;
typedef __attribute__((ext_vector_type(4))) float f32x4;

__device__ __forceinline__ float b2f(bf16_t x) { return __bfloat162float(x); }
__device__ __forceinline__ float sane(float x) { return isfinite(x) ? x : 0.f; }
__device__ __forceinline__ unsigned short f2bu(float x) {
    union { bf16_t b; unsigned short u; } c; c.b = __float2bfloat16(x); return c.u;
}

// dual-dtype load/store: external float tensors are f32 or bf16, per runtime flag
__device__ __forceinline__ float ldf(const void* p, size_t i, int f32) {
    return f32 ? ((const float*)p)[i] : __bfloat162float(((const bf16_t*)p)[i]);
}
__device__ __forceinline__ void stf(void* p, size_t i, float v, int f32) {
    if (f32) ((float*)p)[i] = v;
    else     ((bf16_t*)p)[i] = __float2bfloat16(v);
}

// ---- dtype probe: basis_freq[0] == 1.0f exactly; f32 word = 0x3F800000 ----
__global__ void detect_dtype(const unsigned int* w, int* flag) {
    if (threadIdx.x == 0 && blockIdx.x == 0) *flag = (w[0] == 0x3F800000u) ? 1 : 0;
}

// ---- wcomb_r = W_feat_r @ Wr_r (bf16 out, internal) ----
__global__ void combine_w(const void* Wb, const void* Wr0,
                          const void* Wc, const void* Wr1,
                          const void* Wr, const void* Wr2,
                          bf16_t* out, const int* flagp) {
    int f = *flagp;
    const void* A = blockIdx.x == 0 ? Wb : (blockIdx.x == 1 ? Wc : Wr);
    const void* B = blockIdx.x == 0 ? Wr0 : (blockIdx.x == 1 ? Wr1 : Wr2);
    bf16_t* O = out + (size_t)blockIdx.x * 4096;
    for (int idx = threadIdx.x; idx < 4096; idx += blockDim.x) {
        int i = idx >> 6, j = idx & 63;
        float acc = 0.f;
        for (int k = 0; k < 64; ++k)
            acc = fmaf(ldf(A, i * 64 + k, f), ldf(B, k * 64 + j, f), acc);
        O[idx] = __float2bfloat16(acc);
    }
}

// ============================================================================
// Generic MFMA GEMM: out = act(A[M,K] @ W[K,64] + bias), K in {64,128}.
// Block = 256 thr = 4 waves; 64 rows per block, wave handles a 16-row strip.
// MFMA 16x16x32 bf16. Layouts (HW-verified per guide):
//   A frag:  lane holds A[m0+(lane&15)][kk + (lane>>4)*8 + j], j=0..7
//   B frag:  lane holds W[kk + (lane>>4)*8 + j][n0 + (lane&15)]
//   C/D:     row = m0 + (lane>>4)*4 + reg, col = n0 + (lane&15)
// W staged in LDS pre-swizzled so each B frag is one ds_read_b128.
// mode 0: out = bf16 internal, no bias/act. mode 1: out = external dtype,
//         v += hext(+relb); elu; store at row+orow0.
// ============================================================================
__global__ __launch_bounds__(256) void gemm_n64(
    const void* __restrict__ A, int a_internal,
    const void* __restrict__ W, int w_internal,
    const void* __restrict__ hext, const bf16_t* __restrict__ relb,
    void* __restrict__ out, int out_mode, int orow0,
    int M, int K, const int* flagp) {
    __shared__ short WL[128 * 64];   // 16 KB max (K*64 used)
    int f = *flagp;
    int a_f32 = a_internal ? 0 : f;
    int w_f32 = w_internal ? 0 : f;
    for (int i = threadIdx.x; i < K * 64; i += 256) {
        int j = i & 7, ln = (i >> 3) & 63, p = i >> 9;
        int kk4 = p >> 2, n0t = p & 3;
        int srow = kk4 * 32 + (ln >> 4) * 8 + j;
        int scol = n0t * 16 + (ln & 15);
        float wv = w_f32 ? ((const float*)W)[srow * 64 + scol]
                         : b2f(((const bf16_t*)W)[srow * 64 + scol]);
        WL[i] = (short)f2bu(wv);
    }
    __syncthreads();
    int lane = threadIdx.x & 63;
    int wv = threadIdx.x >> 6;
    int q = lane >> 4, nl = lane & 15;
    int m0 = blockIdx.x * 64 + wv * 16;
    if (m0 >= M) return;
    int arow = m0 + nl; if (arow >= M) arow = M - 1;
    f32x4 acc[4];
#pragma unroll
    for (int t = 0; t < 4; ++t) acc[t] = (f32x4){0.f, 0.f, 0.f, 0.f};
    int KK = K >> 5;
    for (int kk4 = 0; kk4 < KK; ++kk4) {
        short8 af;
        size_t abase = (size_t)arow * K + kk4 * 32 + q * 8;
        if (a_f32) {
            const f32x4* ap = (const f32x4*)((const float*)A + abase);
            f32x4 x0 = ap[0], x1 = ap[1];
#pragma unroll
            for (int j = 0; j < 4; ++j) {
                af[j] = (short)f2bu(x0[j]);
                af[4 + j] = (short)f2bu(x1[j]);
            }
        } else {
            af = *(const short8*)((const bf16_t*)A + abase);
        }
#pragma unroll
        for (int n0t = 0; n0t < 4; ++n0t) {
            short8 bfr = *(const short8*)&WL[(((kk4 << 2) + n0t) * 64 + lane) * 8];
            acc[n0t] = __builtin_amdgcn_mfma_f32_16x16x32_bf16(af, bfr, acc[n0t], 0, 0, 0);
        }
    }
#pragma unroll
    for (int n0t = 0; n0t < 4; ++n0t) {
#pragma unroll
        for (int r = 0; r < 4; ++r) {
            int row = m0 + q * 4 + r;
            if (row >= M) continue;
            int col = n0t * 16 + nl;
            float v = acc[n0t][r];
            if (out_mode == 1) {
                v += ldf(hext, (size_t)row * 64 + col, f);
                if (relb) v += b2f(relb[(size_t)row * 64 + col]);
                v = v > 0.f ? v : expm1f(v);
                stf(out, (size_t)(row + orow0) * 64 + col, sane(v), f);
            } else {
                ((bf16_t*)out)[(size_t)row * 64 + col] = __float2bfloat16(v);
            }
        }
    }
}

// ---- one-launch degree histogram over all edge sets ----
__global__ __launch_bounds__(256) void hist_all(
    const int* __restrict__ e_uid, const int* __restrict__ e_iid,
    const int* __restrict__ eb_dst, const int* __restrict__ ec_dst,
    const int* __restrict__ er_dst, int* __restrict__ deg) {
    int t = blockIdx.x * blockDim.x + threadIdx.x;
    if (t < NE) {
        atomicAdd(deg + e_uid[t], 1);
        atomicAdd(deg + NU + e_iid[t], 1);
    } else if (t < NE + NEB) {
        atomicAdd(deg + 2 * NU + eb_dst[t - NE], 1);
    } else if (t < NE + NEB + NEC) {
        atomicAdd(deg + 2 * NU + ec_dst[t - NE - NEB], 1);
    } else if (t < NALL) {
        atomicAdd(deg + 2 * NU + er_dst[t - NE - NEB - NEC], 1);
    }
}

// ---- exclusive scan over SCAN_N ints ----
__global__ __launch_bounds__(256) void scan1(const int* __restrict__ deg,
                                             int* __restrict__ off,
                                             int* __restrict__ ctot) {
    __shared__ int part[256];
    int base = blockIdx.x * SCAN_CHUNK + threadIdx.x * 8;
    int v[8]; int s = 0;
#pragma unroll
    for (int k = 0; k < 8; ++k) {
        int idx = base + k;
        v[k] = s;
        s += (idx < SCAN_N) ? deg[idx] : 0;
    }
    part[threadIdx.x] = s;
    __syncthreads();
    for (int o = 1; o < 256; o <<= 1) {
        int t = (threadIdx.x >= o) ? part[threadIdx.x - o] : 0;
        __syncthreads();
        part[threadIdx.x] += t;
        __syncthreads();
    }
    int texc = (threadIdx.x == 0) ? 0 : part[threadIdx.x - 1];
#pragma unroll
    for (int k = 0; k < 8; ++k) {
        int idx = base + k;
        if (idx < SCAN_N) off[idx] = texc + v[k];
    }
    if (threadIdx.x == 255) ctot[blockIdx.x] = part[255];
}
__global__ void scan2(const int* __restrict__ ctot, int* __restrict__ coff) {
    if (threadIdx.x == 0 && blockIdx.x == 0) {
        int s = 0;
        for (int i = 0; i < SCAN_NCHUNK; ++i) { coff[i] = s; s += ctot[i]; }
    }
}
__global__ __launch_bounds__(256) void scan3(int* __restrict__ off,
                                             const int* __restrict__ coff) {
    int add = coff[blockIdx.x];
    int base = blockIdx.x * SCAN_CHUNK + threadIdx.x;
#pragma unroll
    for (int k = 0; k < 8; ++k) {
        int idx = base + k * 256;
        if (idx < SCAN_N) off[idx] += add;
    }
}

// ---- wave-per-edge: dots + exp + payload scatter (both directions) ----
// payload: {nbr | pos<<17,  f16(p_long) | f16(p_short)<<16}
__global__ __launch_bounds__(256) void purchase_edges(
    const bf16_t* __restrict__ uh, const bf16_t* __restrict__ ih,
    const void* __restrict__ u_pos_k, const void* __restrict__ i_pos_k,
    const void* __restrict__ basis_freq, const void* __restrict__ phase,
    const void* __restrict__ e_time,
    const int* __restrict__ e_uid, const int* __restrict__ e_iid,
    const int* __restrict__ pos_u, const int* __restrict__ pos_i,
    int* __restrict__ cur, uint2* __restrict__ perm, const int* flagp) {
    __shared__ bf16_t pkU[50 * 64], pkI[50 * 64];   // 12.8 KB
    int f = *flagp;
    for (int i = threadIdx.x; i < 50 * 64; i += 256) {
        pkU[i] = __float2bfloat16(ldf(u_pos_k, i, f));
        pkI[i] = __float2bfloat16(ldf(i_pos_k, i, f));
    }
    __syncthreads();
    int lane = threadIdx.x & 63;
    int e = (blockIdx.x * blockDim.x + threadIdx.x) >> 6;
    if (e >= NE) return;
    int uid = e_uid[e], iid = e_iid[e], pu = pos_u[e], pi = pos_i[e];
    float t = ldf(e_time, e, f);
    float te = __cosf(fmaf(t, ldf(basis_freq, lane, f), ldf(phase, lane, f)));
    float hu = b2f(uh[(size_t)uid * 64 + lane]);
    float hi = b2f(ih[(size_t)iid * 64 + lane]);
    float d_lu = (hi + b2f(pkU[pu * 64 + lane]) + te) * hu;
    float d_sh = hi * hu;
    float d_li = (hu + b2f(pkI[pi * 64 + lane]) + te) * hi;
#pragma unroll
    for (int o = 32; o; o >>= 1) {
        d_lu += __shfl_xor(d_lu, o, 64);
        d_sh += __shfl_xor(d_sh, o, 64);
        d_li += __shfl_xor(d_li, o, 64);
    }
    if (lane == 0) {
        float p_lu = __expf(fminf(d_lu * 0.125f, 10.f));   // clamp protects f16 pack
        float p_sh = __expf(fminf(d_sh * 0.125f, 10.f));
        float p_li = __expf(fminf(d_li * 0.125f, 10.f));
        unsigned pkt_u = (unsigned)__half_as_ushort(__float2half(p_lu))
                       | ((unsigned)__half_as_ushort(__float2half(p_sh)) << 16);
        unsigned pkt_i = (unsigned)__half_as_ushort(__float2half(p_li))
                       | ((unsigned)__half_as_ushort(__float2half(p_sh)) << 16);
        int s1 = atomicAdd(cur + uid, 1);
        perm[s1] = make_uint2((unsigned)iid | ((unsigned)pu << 17), pkt_u);
        int s2 = atomicAdd(cur + NU + iid, 1);
        perm[s2] = make_uint2((unsigned)uid | ((unsigned)pi << 17), pkt_i);
    }
}

// ---- relation edge payload scatter (thread per edge) ----
__global__ __launch_bounds__(256) void scatter_rel_all(
    const int* __restrict__ eb_src, const int* __restrict__ eb_dst,
    const int* __restrict__ ec_src, const int* __restrict__ ec_dst,
    const int* __restrict__ er_src, const int* __restrict__ er_dst,
    int* __restrict__ cur, uint2* __restrict__ perm) {
    int t = blockIdx.x * blockDim.x + threadIdx.x;
    if (t < NEB) {
        int p = atomicAdd(cur + 2 * NU + eb_dst[t], 1);
        perm[p] = make_uint2((unsigned)eb_src[t], 0u);
    } else if (t < NEB + NEC) {
        int e = t - NEB;
        int p = atomicAdd(cur + 2 * NU + ec_dst[e], 1);
        perm[p] = make_uint2((unsigned)(ec_src[e] + NB_) | (1u << 17), 0u);
    } else if (t < NRELE) {
        int e = t - NEB - NEC;
        int p = atomicAdd(cur + 2 * NU + er_dst[e], 1);
        perm[p] = make_uint2((unsigned)(er_src[e] + NB_ + NC_) | (2u << 17), 0u);
    }
}

// ---- gather: reduction-free softmax aggregation; writes agg rows (+relb) ----
__global__ __launch_bounds__(256) void gather_agg(
    const bf16_t* __restrict__ uh, const bf16_t* __restrict__ ih,
    const void* __restrict__ u_pos, const void* __restrict__ i_pos,
    const int* __restrict__ off, const uint2* __restrict__ perm,
    const bf16_t* __restrict__ fW,
    bf16_t* __restrict__ agg, bf16_t* __restrict__ relb,
    const int* flagp, int phase) {            // phase 0 = user, 1 = item
    __shared__ bf16_t posvL[50 * 64];         // 6.4 KB
    int f = *flagp;
    const void* pv = phase ? i_pos : u_pos;
    for (int i = threadIdx.x; i < 50 * 64; i += 256)
        posvL[i] = __float2bfloat16(ldf(pv, i, f));
    __syncthreads();
    int lane = threadIdx.x & 63;
    int wave = threadIdx.x >> 6;
    int vtx = blockIdx.x * 4 + wave;
    if (vtx >= (phase ? NI : NU)) return;
    const bf16_t* other = phase ? uh : ih;
    int seg = phase ? NU + vtx : vtx;
    int j0 = off[seg], j1 = off[seg + 1];
    float s1 = 0.f, s2 = 0.f, a0 = 0.f, a1 = 0.f;
    for (int cb = j0; cb < j1; cb += 64) {
        int m = j1 - cb; if (m > 64) m = 64;
        uint2 pay = make_uint2(0u, 0u);
        if (lane < m) pay = perm[cb + lane];
        unsigned px0 = (unsigned)__shfl((int)pay.x, 0, 64);
        unsigned py0 = (unsigned)__shfl((int)pay.y, 0, 64);
        int nbr0 = px0 & 0x1FFFF; int pos0 = (px0 >> 17) & 63;
        float ho0 = b2f(other[(size_t)nbr0 * 64 + lane]);
        for (int k = 0; k < m; ++k) {
            unsigned px1 = 0, py1 = 0; int nbr1 = 0, pos1 = 0; float ho1 = 0.f;
            if (k + 1 < m) {
                px1 = (unsigned)__shfl((int)pay.x, k + 1, 64);
                py1 = (unsigned)__shfl((int)pay.y, k + 1, 64);
                nbr1 = px1 & 0x1FFFF; pos1 = (px1 >> 17) & 63;
                ho1 = b2f(other[(size_t)nbr1 * 64 + lane]);
            }
            float p1 = __half2float(__ushort_as_half((unsigned short)(py0 & 0xFFFF)));
            float p2 = __half2float(__ushort_as_half((unsigned short)(py0 >> 16)));
            a0 = fmaf(p1, ho0 + b2f(posvL[pos0 * 64 + lane]), a0);
            a1 = fmaf(p2, ho0, a1);
            s1 += p1; s2 += p2;
            px0 = px1; py0 = py1; nbr0 = nbr1; pos0 = pos1; ho0 = ho1;
        }
    }
    a0 *= 1.f / (s1 + 1e-9f);
    a1 *= 1.f / (s2 + 1e-9f);
    agg[(size_t)vtx * 128 + lane] = __float2bfloat16(a0);
    agg[(size_t)vtx * 128 + 64 + lane] = __float2bfloat16(a1);
    if (phase) {
        float r0 = 0.f, r1 = 0.f, r2 = 0.f; int c0 = 0, c1 = 0, c2 = 0;
        int k0 = off[2 * NU + vtx], k1 = off[2 * NU + vtx + 1];
        for (int cb = k0; cb < k1; cb += 64) {
            int m = k1 - cb; if (m > 64) m = 64;
            unsigned px = (lane < m) ? perm[cb + lane].x : 0u;
            for (int k = 0; k < m; ++k) {
                unsigned u = (unsigned)__shfl((int)px, k, 64);
                int row = u & 0x1FFFF; int r = (u >> 17) & 3;
                float fv = b2f(fW[(size_t)row * 64 + lane]);
                if (r == 0)      { r0 += fv; c0++; }
                else if (r == 1) { r1 += fv; c1++; }
                else             { r2 += fv; c2++; }
            }
        }
        float relv = r0 * (1.f / fmaxf((float)c0, 1.f))
                   + r1 * (1.f / fmaxf((float)c1, 1.f))
                   + r2 * (1.f / fmaxf((float)c2, 1.f));
        relb[(size_t)vtx * 64 + lane] = __float2bfloat16(relv);
    }
}

extern "C" void kernel_launch(void* const* d_in, const int* in_sizes, int n_in,
                              void* d_out, int out_size, void* d_ws, size_t ws_size,
                              hipStream_t stream) {
    const void* user_h     = d_in[0];
    const void* item_h     = d_in[1];
    const void* brand_feat = d_in[2];
    const void* cat_feat   = d_in[3];
    const void* rel_feat   = d_in[4];
    const void* Wu   = d_in[5];
    const void* Wi   = d_in[6];
    const void* Wb   = d_in[7];
    const void* Wc   = d_in[8];
    const void* Wr   = d_in[9];
    const void* Wg_u = d_in[10];
    const void* Wg_i = d_in[11];
    const void* u_pos   = d_in[12];
    const void* u_pos_k = d_in[13];
    const void* i_pos   = d_in[14];
    const void* i_pos_k = d_in[15];
    const void* basis_freq = d_in[16];
    const void* phase      = d_in[17];
    const void* Wr0 = d_in[18];
    const void* Wr1 = d_in[19];
    const void* Wr2 = d_in[20];
    const void* e_time = d_in[21];
    const int* e_iid  = (const int*)d_in[22];
    const int* e_uid  = (const int*)d_in[23];
    const int* pos_u  = (const int*)d_in[24];
    const int* pos_i  = (const int*)d_in[25];
    const int* eb_src = (const int*)d_in[26];
    const int* eb_dst = (const int*)d_in[27];
    const int* ec_src = (const int*)d_in[28];
    const int* ec_dst = (const int*)d_in[29];
    const int* er_src = (const int*)d_in[30];
    const int* er_dst = (const int*)d_in[31];

    char* base = (char*)d_ws;
    size_t off_b = 0;
    auto alloc = [&](size_t bytes) { size_t p = off_b; off_b = (off_b + bytes + 511) & ~(size_t)511; return p; };
    size_t o_flag  = alloc(512);
    size_t o_uh    = alloc((size_t)NU * 64 * 2);                 // 12.8 MB
    size_t o_ih    = alloc((size_t)NI * 64 * 2);                 // 12.8 MB
    size_t o_fW    = alloc((size_t)(NB_ + NC_ + NR_ + 64) * 64 * 2); // 7.3 MB
    size_t o_wcomb = alloc((size_t)3 * 4096 * 2);
    size_t o_deg   = alloc((size_t)SCAN_N * 4);
    size_t o_off   = alloc((size_t)SCAN_N * 4);
    size_t o_cur   = alloc((size_t)SCAN_N * 4);
    size_t o_ctot  = alloc((size_t)SCAN_NCHUNK * 4);
    size_t o_coff  = alloc((size_t)SCAN_NCHUNK * 4);
    size_t o_perm  = alloc((size_t)NPERM * 8);                   // 15.2 MB
    size_t o_agg   = alloc((size_t)(NU + 64) * 128 * 2);         // 25.6 MB (reused per phase)
    size_t o_relb  = alloc((size_t)(NI + 64) * 64 * 2);          // 12.8 MB

    int*    flagp = (int*)(base + o_flag);
    bf16_t* uh    = (bf16_t*)(base + o_uh);
    bf16_t* ih    = (bf16_t*)(base + o_ih);
    bf16_t* fW    = (bf16_t*)(base + o_fW);
    bf16_t* wcomb = (bf16_t*)(base + o_wcomb);
    int*    deg   = (int*)(base + o_deg);
    int*    offp  = (int*)(base + o_off);
    int*    cur   = (int*)(base + o_cur);
    int*    ctot  = (int*)(base + o_ctot);
    int*    coff  = (int*)(base + o_coff);
    uint2*  perm  = (uint2*)(base + o_perm);
    bf16_t* agg   = (bf16_t*)(base + o_agg);
    bf16_t* relb  = (bf16_t*)(base + o_relb);

    hipMemsetAsync(deg, 0, (size_t)SCAN_N * 4, stream);
    detect_dtype<<<1, 64, 0, stream>>>((const unsigned int*)basis_freq, flagp);

    combine_w<<<3, 256, 0, stream>>>(Wb, Wr0, Wc, Wr1, Wr, Wr2, wcomb, flagp);

    // transforms via MFMA GEMM (mode 0: bf16 out, no bias)
    gemm_n64<<<(NU + 63) / 64, 256, 0, stream>>>(user_h, 0, Wu, 0, nullptr, nullptr,
                                                 uh, 0, 0, NU, 64, flagp);
    gemm_n64<<<(NI + 63) / 64, 256, 0, stream>>>(item_h, 0, Wi, 0, nullptr, nullptr,
                                                 ih, 0, 0, NI, 64, flagp);
    gemm_n64<<<(NB_ + 63) / 64, 256, 0, stream>>>(brand_feat, 0, wcomb, 1, nullptr, nullptr,
                                                  fW, 0, 0, NB_, 64, flagp);
    gemm_n64<<<(NC_ + 63) / 64, 256, 0, stream>>>(cat_feat, 0, wcomb + 4096, 1, nullptr, nullptr,
                                                  fW + (size_t)NB_ * 64, 0, 0, NC_, 64, flagp);
    gemm_n64<<<(NR_ + 63) / 64, 256, 0, stream>>>(rel_feat, 0, wcomb + 8192, 1, nullptr, nullptr,
                                                  fW + (size_t)(NB_ + NC_) * 64, 0, 0, NR_, 64, flagp);

    hist_all<<<(NALL + 255) / 256, 256, 0, stream>>>(e_uid, e_iid, eb_dst, ec_dst, er_dst, deg);
    scan1<<<SCAN_NCHUNK, 256, 0, stream>>>(deg, offp, ctot);
    scan2<<<1, 64, 0, stream>>>(ctot, coff);
    scan3<<<SCAN_NCHUNK, 256, 0, stream>>>(offp, coff);
    hipMemcpyAsync(cur, offp, (size_t)SCAN_N * 4, hipMemcpyDeviceToDevice, stream);

    purchase_edges<<<NE / 4, 256, 0, stream>>>(uh, ih, u_pos_k, i_pos_k, basis_freq, phase,
                                               e_time, e_uid, e_iid, pos_u, pos_i,
                                               cur, perm, flagp);
    scatter_rel_all<<<(NRELE + 255) / 256, 256, 0, stream>>>(eb_src, eb_dst, ec_src, ec_dst,
                                                             er_src, er_dst, cur, perm);

    // user phase
    gather_agg<<<VBLK, 256, 0, stream>>>(uh, ih, u_pos, i_pos, offp, perm, fW,
                                         agg, relb, flagp, 0);
    gemm_n64<<<(NU + 63) / 64, 256, 0, stream>>>(agg, 1, Wg_u, 0, user_h, nullptr,
                                                 d_out, 1, 0, NU, 128, flagp);
    // item phase (reuses agg)
    gather_agg<<<VBLK, 256, 0, stream>>>(uh, ih, u_pos, i_pos, offp, perm, fW,
                                         agg, relb, flagp, 1);
    gemm_n64<<<(NI + 63) / 64, 256, 0, stream>>>(agg, 1, Wg_i, 0, item_h, relb,
                                                 d_out, 1, NU, NI, 128, flagp);
}